// Round 6
// baseline (15536.653 us; speedup 1.0000x reference)
//
#include <hip/hip_runtime.h>
#include <cstdint>
#include <cstddef>

// Problem constants
#define BB   64     // batch
#define TT   512    // time steps
#define HH   256    // hidden
#define G4   1024   // 4*H
#define NL   8      // layers
#define NG   4      // batch groups
#define BG   16     // batch rows per group (NG*BG = BB)

// Watchdog: poll breaks after this many iterations and proceeds (bounded
// wrong-answer instead of GPU hang). Never triggers when protocol is sound.
#define POLL_BOUND (1 << 18)

typedef _Float16 half8 __attribute__((ext_vector_type(8)));
typedef float   floatx4 __attribute__((ext_vector_type(4)));
typedef float   floatx4s __attribute__((ext_vector_type(4)));

__device__ __forceinline__ float sigm(float v)   { return 1.0f / (1.0f + __expf(-v)); }
__device__ __forceinline__ float tanh_f(float v) { return 1.0f - 2.0f / (__expf(2.0f * v) + 1.0f); }

// ---- coherence helpers (ONLY the proven system-scope primitives) ----------
// Producer: data stores sc0sc1 -> s_waitcnt vmcnt(0) -> flag store sc0sc1.
// Consumer: poll flag sc0sc1; then PLAIN cached loads of the data (each data
// address is written exactly once per launch and only read after the flag:
// first-touch L2 fill pulls post-store bytes from IF$). Proven in the 1908us
// baseline and the R5 pass.
__device__ __forceinline__ void gstore8_x(_Float16* p, half8 d) {
  asm volatile("global_store_dwordx4 %0, %1, off sc0 sc1" :: "v"(p), "v"(d) : "memory");
}
__device__ __forceinline__ void stdword_x(int* p, int v) {
  asm volatile("global_store_dword %0, %1, off sc0 sc1" :: "v"(p), "v"(v) : "memory");
}
__device__ __forceinline__ void wait_vm0() {
  asm volatile("s_waitcnt vmcnt(0)" ::: "memory");
}
__device__ __forceinline__ int ldflag_x(const int* p) {
  int v; asm volatile("global_load_dword %0, %1, off sc0 sc1" : "=v"(v) : "v"(p) : "memory");
  wait_vm0(); return v;
}

// hseq global layout per layer per t: [kblk=32][b=64][8] fp16 (A-frag friendly)
#define TSTRIDE ((size_t)32 * BB * 8)         // 16384 elems per t
#define LSTRIDE ((size_t)TT * TSTRIDE)        // 8,388,608 elems per layer (16MB)

// ---------------------------------------------------------------------------
// xg0 table: table[v][n] = sum_e emb[v][e] * Wih0[n][e]   (biases NOT included)
__global__ void build_xg0(const float* __restrict__ emb, const float* __restrict__ Wih0,
                          float* __restrict__ table) {
  int i = blockIdx.x * 256 + threadIdx.x;
  if (i >= 23 * G4) return;
  int v = i >> 10, n = i & (G4 - 1);
  float a = 0.f;
#pragma unroll
  for (int e = 0; e < 16; ++e) a += emb[v * 16 + e] * Wih0[n * 16 + e];
  table[i] = a;
}

// ---------------------------------------------------------------------------
// Persistent weight-stationary LSTM.
// grid = NL*NG = 32 WGs x 1024 threads (16 waves). WG (l, g) owns layer l,
// batch rows 16g..16g+15, ALL 1024 gate rows.
//
// Wave wv owns hidden units 16wv..16wv+15 (all 4 gates): its 4 MFMA N-tiles
// are gate rows {nt*256 + 16wv + (lane&15)} for nt=i,f,g,o. Weights stay in
// 256 VGPRs/lane as pre-converted fp16 B-fragments for the whole kernel.
//
// Per step (ONE barrier):
//   poll fwd flag (cached lookahead, usually free) ->
//   wave0: publish h(t-1) LDS->hseq (sc0sc1, drains under this step) ->
//   fwd A-frags: plain cached loads of hseq[l-1][t] (first-touch after flag)
//   rec A-frags: LDS hbuf[cur] -> 64 MFMAs -> cell fully in-register
//   (lane's acc[nt][r] = gate nt, batch q*4+r, hidden 16wv+(lane&15)) ->
//   write h(t) to hbuf[cur^1] -> wave0: vmcnt(0); flag = t -> barrier; flip.
// Recurrent dependency never leaves the WG. Forward skew ~2 steps/layer.
__global__ __launch_bounds__(1024, 4) void lstm_pipeline(
    const int*   __restrict__ x,         // [B][T]
    const float* __restrict__ Wih_rest,  // [7][1024][256]
    const float* __restrict__ Whh,       // [8][1024][256]
    const float* __restrict__ bih,       // [8][1024]
    const float* __restrict__ bhh,       // [8][1024]
    const float* __restrict__ xg0t,      // [23][1024] (no biases)
    _Float16* __restrict__ hseq,         // NL * LSTRIDE fp16 (forward edges)
    int* __restrict__ flag)              // [NL][NG] step counters (IF$)
{
  const int l   = blockIdx.x & 7;
  const int g   = blockIdx.x >> 3;
  const int tid = threadIdx.x;
  const int lane = tid & 63;
  const int wv   = tid >> 6;        // wave = hidden-slice (16 units)
  const int q    = lane >> 4;       // quarter: k-chunk select / batch-row block
  const int c    = lane & 15;       // n-col within tile / batch row for A-loads

  __shared__ __align__(16) _Float16 hbuf[2][32 * BG * 8]; // [kc][b][8] 2x8KB
  __shared__ float tlds[23 * G4];                          // layer-0 table (94KB)

  // ---- one-time init -------------------------------------------------------
  // B-fragments: bfr[nt][kt] covers gate rows nt*256+16wv+c, k = kt*32+q*8+j.
  // kt 0..7 = input half (Wih), kt 8..15 = recurrent half (Whh).
  half8 bfr[4][16];
#pragma unroll
  for (int nt = 0; nt < 4; ++nt) {
    const int gr = nt * 256 + wv * 16 + c;
#pragma unroll
    for (int kt = 0; kt < 16; ++kt) {
      const int koff = kt * 32 + q * 8;
      float v[8];
      if (kt < 8) {
        if (l == 0) {
#pragma unroll
          for (int j = 0; j < 8; ++j) v[j] = 0.f;   // layer 0: input via table
        } else {
          const float* src = Wih_rest + ((size_t)(l - 1) * G4 + gr) * HH + koff;
#pragma unroll
          for (int j = 0; j < 8; ++j) v[j] = src[j];
        }
      } else {
        const float* src = Whh + ((size_t)l * G4 + gr) * HH + (koff - 256);
#pragma unroll
        for (int j = 0; j < 8; ++j) v[j] = src[j];
      }
      half8 hv;
#pragma unroll
      for (int j = 0; j < 8; ++j) hv[j] = (_Float16)v[j];
      bfr[nt][kt] = hv;
    }
  }
  // biases (gate nt of hidden unit 16wv+c) -- batch-independent
  float bias[4];
#pragma unroll
  for (int nt = 0; nt < 4; ++nt) {
    const int gr = nt * 256 + wv * 16 + c;
    bias[nt] = bih[l * G4 + gr] + bhh[l * G4 + gr];
  }
  if (l == 0) {
    for (int i = tid; i < 23 * G4; i += 1024) tlds[i] = xg0t[i];
  }
  // agent-scope acquire: invalidate stale L1/L2 lines before cached reads
  if (tid == 0) (void)__hip_atomic_load(flag, __ATOMIC_ACQUIRE, __HIP_MEMORY_SCOPE_AGENT);
  __syncthreads();

  const _Float16* hprev = hseq + (size_t)(l > 0 ? l - 1 : 0) * LSTRIDE;
  _Float16*       hme   = hseq + (size_t)l * LSTRIDE;
  const int* ffwd = flag + (l > 0 ? l - 1 : 0) * NG + g;
  int*       fown = flag + l * NG + g;

  float cst[4] = {0.f, 0.f, 0.f, 0.f};   // c-state: batch q*4+r, hidden 16wv+c
  int   curb  = 0;
  int   fseen = 0;                        // cached fwd-flag value (monotone)

  for (int t = 0; t < TT; ++t) {
    // ---- forward-flag poll (l>0): need h^{l-1}(t) => flag >= t+1 ----------
    if (l > 0 && fseen < t + 1) {
      for (int it = 0; it < POLL_BOUND; ++it) {
        fseen = ldflag_x(ffwd);
        if (fseen >= t + 1) break;
        __builtin_amdgcn_s_sleep(1);
      }
    }

    // ---- wave0: publish h(t-1) = hbuf[curb] -> hseq (stores only; the
    //      vmcnt+flag happen at end of this step, a full step of drain) -----
    if (wv == 0 && t > 0) {
      const _Float16* src = hbuf[curb];
#pragma unroll
      for (int i = 0; i < 8; ++i) {
        const int ch = lane + 64 * i;       // 512 chunks of 16B
        const int kc = ch >> 4, b = ch & 15;
        half8 hv = *(const half8*)(src + ch * 8);
        gstore8_x(hme + (size_t)(t - 1) * TSTRIDE + ((size_t)(kc * 64 + g * BG + b)) * 8, hv);
      }
    }

    // ---- forward A-fragments (plain cached; first-touch after flag) -------
    half8 afw[8];
    if (l > 0) {
      const _Float16* ain = hprev + (size_t)t * TSTRIDE;
#pragma unroll
      for (int kt = 0; kt < 8; ++kt) {
        const int kc = kt * 4 + q;
        afw[kt] = *(const half8*)(ain + ((size_t)(kc * 64 + g * BG + c)) * 8);
      }
    }

    floatx4 acc0 = {0.f, 0.f, 0.f, 0.f};
    floatx4 acc1 = {0.f, 0.f, 0.f, 0.f};
    floatx4 acc2 = {0.f, 0.f, 0.f, 0.f};
    floatx4 acc3 = {0.f, 0.f, 0.f, 0.f};

    // ---- recurrent half: A from LDS hbuf[curb] ----------------------------
    if (t > 0) {
      const _Float16* rin = hbuf[curb];
#pragma unroll
      for (int kt = 0; kt < 8; ++kt) {
        const int kc = kt * 4 + q;
        half8 ar = *(const half8*)(rin + (kc * BG + c) * 8);
        acc0 = __builtin_amdgcn_mfma_f32_16x16x32_f16(ar, bfr[0][8 + kt], acc0, 0, 0, 0);
        acc1 = __builtin_amdgcn_mfma_f32_16x16x32_f16(ar, bfr[1][8 + kt], acc1, 0, 0, 0);
        acc2 = __builtin_amdgcn_mfma_f32_16x16x32_f16(ar, bfr[2][8 + kt], acc2, 0, 0, 0);
        acc3 = __builtin_amdgcn_mfma_f32_16x16x32_f16(ar, bfr[3][8 + kt], acc3, 0, 0, 0);
      }
    }
    // ---- input half (l>0) -------------------------------------------------
    if (l > 0) {
#pragma unroll
      for (int kt = 0; kt < 8; ++kt) {
        acc0 = __builtin_amdgcn_mfma_f32_16x16x32_f16(afw[kt], bfr[0][kt], acc0, 0, 0, 0);
        acc1 = __builtin_amdgcn_mfma_f32_16x16x32_f16(afw[kt], bfr[1][kt], acc1, 0, 0, 0);
        acc2 = __builtin_amdgcn_mfma_f32_16x16x32_f16(afw[kt], bfr[2][kt], acc2, 0, 0, 0);
        acc3 = __builtin_amdgcn_mfma_f32_16x16x32_f16(afw[kt], bfr[3][kt], acc3, 0, 0, 0);
      }
    }

    // ---- cell update, fully in-register -----------------------------------
    // C layout (verified): col = lane&15 (= hidden offset c), row = q*4 + r
    // (= batch within group). acc{0,1,2,3}[r] = gates i,f,g,o.
    _Float16* hdst = hbuf[curb ^ 1];
    const int n   = wv * 16 + c;
    const int kc2 = n >> 3, nj = n & 7;
#pragma unroll
    for (int r = 0; r < 4; ++r) {
      const int b = q * 4 + r;
      float gi = acc0[r] + bias[0];
      float gf = acc1[r] + bias[1];
      float gg = acc2[r] + bias[2];
      float go = acc3[r] + bias[3];
      if (l == 0) {
        const int xv = x[(g * BG + b) * TT + t];
        const float* tb = tlds + xv * G4 + wv * 16 + c;
        gi += tb[0]; gf += tb[256]; gg += tb[512]; go += tb[768];
      }
      const float iv = sigm(gi), fv = sigm(gf), gv = tanh_f(gg), ov = sigm(go);
      cst[r] = fv * cst[r] + iv * gv;
      const float hv = ov * tanh_f(cst[r]);
      hdst[(kc2 * BG + b) * 8 + nj] = (_Float16)hv;
    }

    // ---- end of step: wave0 certifies h(t-1) (stores drained by now) ------
    if (wv == 0 && t > 0) {
      wait_vm0();
      if (lane == 0) stdword_x(fown, t);   // flag = t  <=>  h(t-1) visible
    }
    __syncthreads();
    curb ^= 1;
  }

  // ---- epilogue: publish h(TT-1) + final flag -----------------------------
  if (wv == 0) {
    const _Float16* src = hbuf[curb];
#pragma unroll
    for (int i = 0; i < 8; ++i) {
      const int ch = lane + 64 * i;
      const int kc = ch >> 4, b = ch & 15;
      half8 hv = *(const half8*)(src + ch * 8);
      gstore8_x(hme + (size_t)(TT - 1) * TSTRIDE + ((size_t)(kc * 64 + g * BG + b)) * 8, hv);
    }
    wait_vm0();
    if (lane == 0) stdword_x(fown, TT);
  }
}

// ---------------------------------------------------------------------------
// Final projection: out[b][t][v] = h7[b][t][:] . fc_w[v][:] + fc_b[v]
__global__ __launch_bounds__(256) void fc_kernel(
    const _Float16* __restrict__ hseq7,  // [T][32][64][8] fp16
    const float* __restrict__ fcw,       // [23][256]
    const float* __restrict__ fcb,       // [23]
    float* __restrict__ out)             // [64][512][23]
{
  const int t = blockIdx.x;
  const int tid = threadIdx.x;
  __shared__ __align__(16) _Float16 hbuf[32 * 64 * 8];
  __shared__ float wbuf[23 * 256];
  __shared__ float bbuf[24];

  const _Float16* src = hseq7 + (size_t)t * TSTRIDE;
  for (int i = tid; i < 32 * 64; i += 256)
    ((half8*)hbuf)[i] = ((const half8*)src)[i];
  for (int i = tid; i < 23 * 256; i += 256) wbuf[i] = fcw[i];
  if (tid < 23) bbuf[tid] = fcb[tid];
  __syncthreads();

  for (int o = tid; o < 64 * 23; o += 256) {
    int b = o / 23, v = o - b * 23;
    float acc = bbuf[v];
#pragma unroll 4
    for (int kc = 0; kc < 32; ++kc) {
      half8 hv = *(const half8*)(hbuf + ((kc * 64 + b) << 3));
      const float* wr = wbuf + v * 256 + kc * 8;
#pragma unroll
      for (int j = 0; j < 8; ++j) acc += (float)hv[j] * wr[j];
    }
    out[((size_t)b * TT + t) * 23 + v] = acc;
  }
}

// ---------------------------------------------------------------------------
extern "C" void kernel_launch(void* const* d_in, const int* in_sizes, int n_in,
                              void* d_out, int out_size, void* d_ws, size_t ws_size,
                              hipStream_t stream) {
  const int*   x        = (const int*)d_in[0];
  const float* emb      = (const float*)d_in[1];
  const float* Wih0     = (const float*)d_in[2];
  const float* Wih_rest = (const float*)d_in[3];
  const float* Whh      = (const float*)d_in[4];
  const float* bihp     = (const float*)d_in[5];
  const float* bhhp     = (const float*)d_in[6];
  const float* fcw      = (const float*)d_in[7];
  const float* fcb      = (const float*)d_in[8];
  float* out = (float*)d_out;

  char* ws = (char*)d_ws;
  // ws layout:
  // flag @0: NL*NG*4 = 128B | table @16384 | hseq @131072 (128MB)
  int*      flag  = (int*)ws;
  float*    table = (float*)(ws + 16384);              // 23*1024*4 = 94208 B
  _Float16* hseq  = (_Float16*)(ws + 131072);          // 8 * 16 MB

  hipMemsetAsync(ws, 0, 16384, stream);  // flags
  build_xg0<<<(23 * G4 + 255) / 256, 256, 0, stream>>>(emb, Wih0, table);
  lstm_pipeline<<<NL * NG, 1024, 0, stream>>>(x, Wih_rest, Whh, bihp, bhhp, table, hseq, flag);
  fc_kernel<<<TT, 256, 0, stream>>>(hseq + (size_t)7 * LSTRIDE, fcw, fcb, out);
}

// Round 7
// 3165.458 us; speedup vs baseline: 4.9082x; 4.9082x over previous
//
#include <hip/hip_runtime.h>
#include <cstdint>
#include <cstddef>

// Problem constants
#define BB   64     // batch
#define TT   512    // time steps
#define HH   256    // hidden
#define G4   1024   // 4*H
#define NL   8      // layers
#define NW   32     // workgroups per layer (hidden-unit slices)
#define HPW  8      // hidden units per WG
#define NR   32     // gate rows per WG (4 gates * HPW)

// Watchdog: poll breaks after this many iterations and proceeds (bounded
// wrong-answer instead of GPU hang). Never triggers when protocol is sound.
#define POLL_BOUND (1 << 15)

typedef _Float16 half8 __attribute__((ext_vector_type(8)));
typedef float   floatx4 __attribute__((ext_vector_type(4)));

__device__ __forceinline__ float sigm(float v)   { return 1.0f / (1.0f + __expf(-v)); }
__device__ __forceinline__ float tanh_f(float v) { return 1.0f - 2.0f / (__expf(2.0f * v) + 1.0f); }

// ---- coherence helpers (ONLY the proven system-scope primitives) ----------
// Producer: data stores sc0sc1 -> s_waitcnt vmcnt(0) -> flag store sc0sc1.
// Consumer: poll flag sc0sc1; then PLAIN cached loads of the data (each data
// address is written exactly once per launch and only read after the flag:
// first-touch L2 fill pulls post-store bytes from IF$). Proven at 1908us and
// in the R5/R6 passes.
__device__ __forceinline__ void gstore2_x(_Float16* p, _Float16 d) {
  unsigned int ui = (unsigned int)__builtin_bit_cast(unsigned short, d);
  asm volatile("global_store_short %0, %1, off sc0 sc1" :: "v"(p), "v"(ui) : "memory");
}
__device__ __forceinline__ void stdword_x(int* p, int v) {
  asm volatile("global_store_dword %0, %1, off sc0 sc1" :: "v"(p), "v"(v) : "memory");
}
__device__ __forceinline__ void wait_vm0() {
  asm volatile("s_waitcnt vmcnt(0)" ::: "memory");
}
__device__ __forceinline__ int ldflag_x(const int* p) {
  int v; asm volatile("global_load_dword %0, %1, off sc0 sc1" : "=v"(v) : "v"(p) : "memory");
  wait_vm0(); return v;
}

// hseq layout per layer: [t][kblk=H/8=32][b=64][8] fp16 (MFMA A-fragment friendly)
#define TSTRIDE ((size_t)32 * BB * 8)         // 16384 elems per t
#define LSTRIDE ((size_t)TT * TSTRIDE)        // 8,388,608 elems per layer (16 MB)

// ---------------------------------------------------------------------------
// xg0 table: table[v][n] = sum_e emb[v][e] * Wih0[n][e]   (biases NOT included)
__global__ void build_xg0(const float* __restrict__ emb, const float* __restrict__ Wih0,
                          float* __restrict__ table) {
  int i = blockIdx.x * 256 + threadIdx.x;
  if (i >= 23 * G4) return;
  int v = i >> 10, n = i & (G4 - 1);
  float a = 0.f;
#pragma unroll
  for (int e = 0; e < 16; ++e) a += emb[v * 16 + e] * Wih0[n * 16 + e];
  table[i] = a;
}

// ---------------------------------------------------------------------------
// Persistent pipelined LSTM -- the PROVEN 1908us structure (8 layers x 32
// slices x 256 thr, LDS-resident weights, sc0sc1 exchange) with three
// surgical latency cuts, ONE barrier per step (was 3):
//  (J) in-register gates: a wave's two N-tiles are {i,f} and {g,o} of its 8
//      units; two shfl_xor(8) complete each lane's i/f/g/o -> cell in-register
//      (glds + barrier B deleted).
//  (P) direct publish: cell lanes store h as 2B sc0sc1 stores; 8-lane groups
//      coalesce into the same 16B segments wave0 used to write (hl + barrier
//      C + staging read deleted).
//  (F) flag aggregation: each wave vmcnt(0)s its own stores then LDS-
//      atomicAdd; the 4th wave releases the slice flag -- still ordered after
//      ALL data-store acks. Consumer protocol byte-identical to baseline.
__global__ __launch_bounds__(256, 1) void lstm_pipeline(
    const int*   __restrict__ x,         // [B][T]
    const float* __restrict__ Wih_rest,  // [7][1024][256]
    const float* __restrict__ Whh,       // [8][1024][256]
    const float* __restrict__ bih,       // [8][1024]
    const float* __restrict__ bhh,       // [8][1024]
    const float* __restrict__ xg0t,      // [23][1024]
    _Float16* __restrict__ hseq,         // NL * LSTRIDE fp16
    int* __restrict__ cnt)               // [NL][NW] step counters (IF$)
{
  const int l   = blockIdx.x & 7;
  const int w   = blockIdx.x >> 3;
  const int tid = threadIdx.x;
  const int lane = tid & 63;
  const int p    = tid >> 6;        // wave index = M-tile index (batch/16)

  __shared__ __align__(16) _Float16 wlds[64 * NR * 8]; // [kc 0..63][n 0..31][8]
  __shared__ float  blds[NR];
  __shared__ float  tlds[23 * NR];
  __shared__ int    pubcnt;

  // ---- one-time init: gather this WG's 32 gate rows into LDS as fp16 ----
  // wlds n-rows: 0..7 = gate i (units 0..7), 8..15 = f, 16..23 = g, 24..31 = o
  for (int idx = tid; idx < 64 * NR; idx += 256) {
    int kc = idx >> 5;          // 0..31 input half, 32..63 recurrent half
    int n  = idx & 31;
    int g = n >> 3, jl = n & 7;
    int gr = g * 256 + w * HPW + jl;
    float v[8];
    if (kc < 32) {
      if (l == 0) { for (int j = 0; j < 8; ++j) v[j] = 0.f; }
      else {
        const float* src = Wih_rest + ((size_t)(l - 1) * G4 + gr) * HH + kc * 8;
        for (int j = 0; j < 8; ++j) v[j] = src[j];
      }
    } else {
      const float* src = Whh + ((size_t)l * G4 + gr) * HH + (kc - 32) * 8;
      for (int j = 0; j < 8; ++j) v[j] = src[j];
    }
    _Float16* dst = wlds + (size_t)idx * 8;
    for (int j = 0; j < 8; ++j) dst[j] = (_Float16)v[j];
  }
  if (tid < NR) {
    int g = tid >> 3, jl = tid & 7;
    int gr = g * 256 + w * HPW + jl;
    blds[tid] = bih[l * G4 + gr] + bhh[l * G4 + gr];
  }
  if (l == 0) {
    for (int idx = tid; idx < 23 * NR; idx += 256) {
      int v = idx >> 5, n = idx & 31;
      int g = n >> 3, jl = n & 7;
      tlds[idx] = xg0t[v * G4 + g * 256 + w * HPW + jl];
    }
  }
  if (tid == 0) pubcnt = 0;
  // agent-scope acquire: invalidate stale L1/L2 lines before cached h reads
  if (tid == 0) (void)__hip_atomic_load(cnt, __ATOMIC_ACQUIRE, __HIP_MEMORY_SCOPE_AGENT);
  __syncthreads();

  const int arow = p * 16 + (lane & 15);  // A-fragment batch row
  const int kq   = lane >> 4;             // quarter-wave -> k chunk within tile
  const int n0   = lane & 15;             // B-fragment col (tile 0)
  const int n1   = 16 + n0;               // B-fragment col (tile 1)
  const int cu   = lane & 7;              // cell: unit within slice
  const bool cellane = (n0 < 8);          // lanes that own a unit's cell
  const int rowb = p * 16 + kq * 4;       // cell: first of this lane's 4 batch rows

  const _Float16* hin  = hseq + (size_t)(l > 0 ? l - 1 : 0) * LSTRIDE;
  _Float16*       hrec = hseq + (size_t)l * LSTRIDE;

  float bi = 0.f, bf = 0.f, bg = 0.f, bo = 0.f;
  if (cellane) { bi = blds[cu]; bf = blds[8 + cu]; bg = blds[16 + cu]; bo = blds[24 + cu]; }

  float cst[4] = {0.f, 0.f, 0.f, 0.f};    // c-state: batch rowb+r, unit w*8+cu

  for (int t = 0; t < TT; ++t) {
    // ---- parallel polls: wave3 = own layer step t-1, wave2 = layer below ----
    if (t > 0 && p == 3) {
      const int* f = cnt + l * NW;
      for (int it = 0; it < POLL_BOUND; ++it) {
        int v = ldflag_x(f + (lane & 31));
        if (__all(v >= t)) break;
        __builtin_amdgcn_s_sleep(1);
      }
    }
    if (l > 0 && p == 2) {
      const int* f = cnt + (l - 1) * NW;
      for (int it = 0; it < POLL_BOUND; ++it) {
        int v = ldflag_x(f + (lane & 31));
        if (__all(v >= t + 1)) break;
        __builtin_amdgcn_s_sleep(1);
      }
    }
    __syncthreads();   // barrier A -- the ONLY barrier in the step

    // ---- issue ALL loads (input half + recurrent half), plain cached ----
    half8 aA[8], aB[8];
    if (l > 0) {
      const _Float16* ain = hin + (size_t)t * TSTRIDE;
#pragma unroll
      for (int kt = 0; kt < 8; ++kt) {
        int kc = kt * 4 + kq;
        aA[kt] = *(const half8*)(ain + ((size_t)(kc * 64 + arow) << 3));
      }
    }
    if (t > 0) {
      const _Float16* ain = hrec + (size_t)(t - 1) * TSTRIDE;
#pragma unroll
      for (int kt = 0; kt < 8; ++kt) {
        int kc = kt * 4 + kq;
        aB[kt] = *(const half8*)(ain + ((size_t)(kc * 64 + arow) << 3));
      }
    }

    floatx4 acc0 = {0.f, 0.f, 0.f, 0.f};   // tile0: cols = {i x8, f x8}
    floatx4 acc1 = {0.f, 0.f, 0.f, 0.f};   // tile1: cols = {g x8, o x8}
    if (l > 0) {
#pragma unroll
      for (int kt = 0; kt < 8; ++kt) {
        int kc = kt * 4 + kq;
        half8 w0 = *(const half8*)(wlds + ((kc * 32 + n0) << 3));
        half8 w1 = *(const half8*)(wlds + ((kc * 32 + n1) << 3));
        acc0 = __builtin_amdgcn_mfma_f32_16x16x32_f16(aA[kt], w0, acc0, 0, 0, 0);
        acc1 = __builtin_amdgcn_mfma_f32_16x16x32_f16(aA[kt], w1, acc1, 0, 0, 0);
      }
    }
    if (t > 0) {
#pragma unroll
      for (int kt = 0; kt < 8; ++kt) {
        int kc = kt * 4 + kq;
        half8 w0 = *(const half8*)(wlds + (((32 + kc) * 32 + n0) << 3));
        half8 w1 = *(const half8*)(wlds + (((32 + kc) * 32 + n1) << 3));
        acc0 = __builtin_amdgcn_mfma_f32_16x16x32_f16(aB[kt], w0, acc0, 0, 0, 0);
        acc1 = __builtin_amdgcn_mfma_f32_16x16x32_f16(aB[kt], w1, acc1, 0, 0, 0);
      }
    }

    // ---- (J) gate exchange: lane c<8 holds i,g of unit c; partner c+8 holds
    //      f,o of the same unit. Two shfl_xor(8) complete the set. C layout:
    //      col = lane&15, row = kq*4 + r (+ p*16). ----
    float xf[4], xo[4];
#pragma unroll
    for (int r = 0; r < 4; ++r) {
      xf[r] = __shfl_xor(acc0[r], 8);
      xo[r] = __shfl_xor(acc1[r], 8);
    }

    // ---- cell + (P) direct 2B publish (lanes n0<8 only; 8-lane groups
    //      coalesce into 16B segments) ----
    if (cellane) {
      _Float16* dst = hrec + (size_t)t * TSTRIDE + ((size_t)(w * 64 + rowb) << 3) + cu;
#pragma unroll
      for (int r = 0; r < 4; ++r) {
        float gi = acc0[r] + bi;
        float gf = xf[r]   + bf;
        float gg = acc1[r] + bg;
        float go = xo[r]   + bo;
        if (l == 0) {
          const int xv = x[(rowb + r) * TT + t];
          const float* tb = tlds + xv * NR;
          gi += tb[cu]; gf += tb[8 + cu]; gg += tb[16 + cu]; go += tb[24 + cu];
        }
        const float iv = sigm(gi), fv = sigm(gf), gv = tanh_f(gg), ov = sigm(go);
        cst[r] = fv * cst[r] + iv * gv;
        const float hv = ov * tanh_f(cst[r]);
        gstore2_x(dst + (size_t)(r << 3), (_Float16)hv);
      }
    }

    // ---- (F) per-wave ack, then LDS-aggregated flag release ----
    wait_vm0();                         // acks this wave's 4 h stores
    if (lane == 0) {
      int old = atomicAdd(&pubcnt, 1);  // LDS, CU-coherent, ordered after vmcnt
      if (old == 4 * t + 3)             // 4th wave of step t -> all acks done
        stdword_x(cnt + l * NW + w, t + 1);
    }
  }
}

// ---------------------------------------------------------------------------
// Final projection: out[b][t][v] = h7[b][t][:] . fc_w[v][:] + fc_b[v]
__global__ __launch_bounds__(256) void fc_kernel(
    const _Float16* __restrict__ hseq7,  // [T][32][64][8] fp16
    const float* __restrict__ fcw,       // [23][256]
    const float* __restrict__ fcb,       // [23]
    float* __restrict__ out)             // [64][512][23]
{
  const int t = blockIdx.x;
  const int tid = threadIdx.x;
  __shared__ __align__(16) _Float16 hbuf[32 * 64 * 8];
  __shared__ float wbuf[23 * 256];
  __shared__ float bbuf[24];

  const _Float16* src = hseq7 + (size_t)t * TSTRIDE;
  for (int i = tid; i < 32 * 64; i += 256)
    ((half8*)hbuf)[i] = ((const half8*)src)[i];
  for (int i = tid; i < 23 * 256; i += 256) wbuf[i] = fcw[i];
  if (tid < 23) bbuf[tid] = fcb[tid];
  __syncthreads();

  for (int o = tid; o < 64 * 23; o += 256) {
    int b = o / 23, v = o - b * 23;
    float acc = bbuf[v];
#pragma unroll 4
    for (int kc = 0; kc < 32; ++kc) {
      half8 hv = *(const half8*)(hbuf + ((kc * 64 + b) << 3));
      const float* wr = wbuf + v * 256 + kc * 8;
#pragma unroll
      for (int j = 0; j < 8; ++j) acc += (float)hv[j] * wr[j];
    }
    out[((size_t)b * TT + t) * 23 + v] = acc;
  }
}

// ---------------------------------------------------------------------------
extern "C" void kernel_launch(void* const* d_in, const int* in_sizes, int n_in,
                              void* d_out, int out_size, void* d_ws, size_t ws_size,
                              hipStream_t stream) {
  const int*   x        = (const int*)d_in[0];
  const float* emb      = (const float*)d_in[1];
  const float* Wih0     = (const float*)d_in[2];
  const float* Wih_rest = (const float*)d_in[3];
  const float* Whh      = (const float*)d_in[4];
  const float* bihp     = (const float*)d_in[5];
  const float* bhhp     = (const float*)d_in[6];
  const float* fcw      = (const float*)d_in[7];
  const float* fcb      = (const float*)d_in[8];
  float* out = (float*)d_out;

  char* ws = (char*)d_ws;
  // ws layout (proven): cnt @0 (1KB used) | table @16384 | hseq @131072 (128MB)
  int*      cnt   = (int*)ws;
  float*    table = (float*)(ws + 16384);              // 23*1024*4 = 94208 B
  _Float16* hseq  = (_Float16*)(ws + 131072);          // 8 * 16 MB

  hipMemsetAsync(ws, 0, 16384, stream);  // counters
  build_xg0<<<(23 * G4 + 255) / 256, 256, 0, stream>>>(emb, Wih0, table);
  lstm_pipeline<<<NL * NW, 256, 0, stream>>>(x, Wih_rest, Whh, bihp, bhhp, table, hseq, cnt);
  fc_kernel<<<TT, 256, 0, stream>>>(hseq + (size_t)7 * LSTRIDE, fcw, fcb, out);
}